// Round 13
// baseline (57.652 us; speedup 1.0000x reference)
//
#include <hip/hip_runtime.h>

#define P_N 40000
#define M_N 100
#define NBF 2500   // k_fused blocks: 4 waves/block, 4 pillars/wave

typedef _Float16 half2_t __attribute__((ext_vector_type(2)));

__device__ __forceinline__ float bcf(int x) { return __int_as_float(x); }
__device__ __forceinline__ int   bci(float x) { return __float_as_int(x); }
__device__ __forceinline__ float rlf(float v, int l) {
  return bcf(__builtin_amdgcn_readlane(bci(v), l));
}
__device__ __forceinline__ int pk16i(float a, float b) {
  return __builtin_bit_cast(int, __builtin_amdgcn_cvt_pkrtz(a, b));
}
__device__ __forceinline__ half2_t h2(int x) { return __builtin_bit_cast(half2_t, x); }
__device__ __forceinline__ int ih2(half2_t v) { return __builtin_bit_cast(int, v); }

// DPP full-wave64 add-reduce on the VALU pipe (no LDS). Lane 63 holds the sum.
__device__ __forceinline__ float dpp_sum64(float x) {
  x += bcf(__builtin_amdgcn_update_dpp(0, bci(x), 0x111, 0xf, 0xf, true)); // row_shr:1
  x += bcf(__builtin_amdgcn_update_dpp(0, bci(x), 0x112, 0xf, 0xf, true)); // row_shr:2
  x += bcf(__builtin_amdgcn_update_dpp(0, bci(x), 0x114, 0xf, 0xf, true)); // row_shr:4
  x += bcf(__builtin_amdgcn_update_dpp(0, bci(x), 0x118, 0xf, 0xf, true)); // row_shr:8
  x += bcf(__builtin_amdgcn_update_dpp(0, bci(x), 0x142, 0xf, 0xf, true)); // row_bcast:15
  x += bcf(__builtin_amdgcn_update_dpp(0, bci(x), 0x143, 0xf, 0xf, true)); // row_bcast:31
  return x;
}

// u for one point from point-major packs: (x,y)·AB + (z,i)·CD + sE
__device__ __forceinline__ float uPT(int xy, int zi, half2_t AB, half2_t CD, float sE) {
  return __builtin_amdgcn_fdot2(h2(xy), AB,
         __builtin_amdgcn_fdot2(h2(zi), CD, sE, false), false);
}

// ---------------- Kernel 1 (fused): moments + per-pillar raw umax ----------------
// wave = 4 pillars. Phase-batched for ILP at the fixed ~4 waves/SIMD occupancy:
//  P1 load rows -> P2 stage LDS (all pillars) -> P3 all means (12 DPP chains)
//  -> P4 all moments straight-line -> P5 umax loops w/ 2-deep LDS prefetch.
// gamma==1 -> BN scale > 0 -> umax only.

__global__ __launch_bounds__(256) void k_fused(
    const float* __restrict__ px, const float* __restrict__ py,
    const float* __restrict__ pz, const float* __restrict__ pi,
    const int* __restrict__ npp, const int* __restrict__ coors,
    const float* __restrict__ W,
    float* __restrict__ partials, float* __restrict__ umm)
{
  const int lane = threadIdx.x & 63;
  const int wid  = threadIdx.x >> 6;    // 0..3
  const int d    = lane;

  __shared__ int4  stage[4][4][64];     // [wave][pillar][pair-slot]
  __shared__ float red[4][54];

  float w[9];
  #pragma unroll
  for (int c = 0; c < 9; ++c) w[c] = W[c * 64 + d];
  const float sA = w[0] + w[4], sB = w[1] + w[5], sC = w[2] + w[6], sD = w[3];
  const half2_t AB = h2(pk16i(sA, sB));   // point-major weight pairs
  const half2_t CD = h2(pk16i(sC, sD));
  const half2_t H1 = h2(0x3C003C00);      // (1.0h, 1.0h)

  const bool act = lane < 50;
  const int wgid  = blockIdx.x * 4 + wid;
  const int pbase = __builtin_amdgcn_readfirstlane(wgid * 4);

  // uniform metadata (scalar loads)
  const int4 n4 = ((const int4*)npp)[wgid];
  int4 cc[4];
  #pragma unroll
  for (int it = 0; it < 4; ++it) cc[it] = ((const int4*)coors)[pbase + it];

  // ---- P1+P2: load rows, pack to f16, stage point-major to LDS ----
  int u0[4], u1[4], u2[4], u3[4];
  #pragma unroll
  for (int it = 0; it < 4; ++it) {
    const int p_ = pbase + it;
    float2 X = make_float2(0.f, 0.f), Y = X, Z = X, I = X;
    if (act) {
      X = ((const float2*)(px + (size_t)p_ * M_N))[lane];
      Y = ((const float2*)(py + (size_t)p_ * M_N))[lane];
      Z = ((const float2*)(pz + (size_t)p_ * M_N))[lane];
      I = ((const float2*)(pi + (size_t)p_ * M_N))[lane];
    }
    u0[it] = pk16i(X.x, X.y);             // feature-major (slot0, slot1)
    u1[it] = pk16i(Y.x, Y.y);
    u2[it] = pk16i(Z.x, Z.y);
    u3[it] = pk16i(I.x, I.y);
    int4 pm;
    pm.x = pk16i(X.x, Y.x);               // point-major (x,y),(z,i) per point
    pm.y = pk16i(Z.x, I.x);
    pm.z = pk16i(X.y, Y.y);
    pm.w = pk16i(Z.y, I.y);
    stage[wid][it][lane] = pm;
  }

  // ---- P3: all 4 pillars' means (12 interleaved DPP chains) ----
  float sx[4], sy[4], sz[4];
  #pragma unroll
  for (int it = 0; it < 4; ++it) {
    sx[it] = dpp_sum64(__builtin_amdgcn_fdot2(h2(u0[it]), H1, 0.f, false));
    sy[it] = dpp_sum64(__builtin_amdgcn_fdot2(h2(u1[it]), H1, 0.f, false));
    sz[it] = dpp_sum64(__builtin_amdgcn_fdot2(h2(u2[it]), H1, 0.f, false));
  }
  float mxv[4], myv[4], mzv[4], xbv[4], ybv[4];
  #pragma unroll
  for (int it = 0; it < 4; ++it) {
    const int n  = ((const int*)&n4)[it];
    const int nc = n < 1 ? 1 : n;
    const float inv = __builtin_amdgcn_rcpf((float)nc);
    mxv[it] = rlf(sx[it], 63) * inv;
    myv[it] = rlf(sy[it], 63) * inv;
    mzv[it] = rlf(sz[it], 63) * inv;
    xbv[it] = fmaf((float)cc[it].w, 0.16f, 0.08f);            // X0 = 0
    ybv[it] = fmaf((float)cc[it].z, 0.16f, 0.08f - 39.68f);   // Y0 = -39.68
  }

  // ---- P4: all 4 pillars' moments, straight-line ----
  float a1[9] = {};
  float a2[45] = {};
  #pragma unroll
  for (int it = 0; it < 4; ++it) {
    const int n = ((const int*)&n4)[it];
    const unsigned m0 = (2 * lane     < n) ? 0x0000FFFFu : 0u;
    const unsigned m1 = (2 * lane + 1 < n) ? 0xFFFF0000u : 0u;
    const unsigned msk = m0 | m1;
    const half2_t MX = h2(pk16i(mxv[it], mxv[it]));
    const half2_t MY = h2(pk16i(myv[it], myv[it]));
    const half2_t MZ = h2(pk16i(mzv[it], mzv[it]));
    int g[9];
    g[0] = u0[it] & msk;
    g[1] = u1[it] & msk;
    g[2] = u2[it] & msk;
    g[3] = u3[it] & msk;
    g[4] = ih2(h2(u0[it]) - MX) & msk;
    g[5] = ih2(h2(u1[it]) - MY) & msk;
    g[6] = ih2(h2(u2[it]) - MZ) & msk;
    g[7] = pk16i(xbv[it], xbv[it]) & msk;
    g[8] = pk16i(ybv[it], ybv[it]) & msk;
    #pragma unroll
    for (int c = 0; c < 9; ++c)
      a1[c] = __builtin_amdgcn_fdot2(h2(g[c]), H1, a1[c], false);
    int k = 0;
    #pragma unroll
    for (int c = 0; c < 9; ++c) {
      #pragma unroll
      for (int c2 = c; c2 < 9; ++c2) {
        a2[k] = __builtin_amdgcn_fdot2(h2(g[c]), h2(g[c2]), a2[k], false);
        ++k;
      }
    }
  }

  // ---- P5: umax loops with 2-deep LDS prefetch ----
  #pragma unroll
  for (int it = 0; it < 4; ++it) {
    const int p_ = pbase + it;
    const int n  = ((const int*)&n4)[it];
    const float sE = fmaf(-mxv[it], w[4], fmaf(-myv[it], w[5], fmaf(-mzv[it], w[6],
                     fmaf(xbv[it], w[7], ybv[it] * w[8]))));
    const int4* sp = &stage[wid][it][0];

    float um0 = -3.0e38f, um1 = -3.0e38f;
    const int nq  = n >> 2;              // full quads
    const int rem = n & 3;
    int4 qa = sp[0], qb = sp[1];
    for (int l = 0; l < nq; ++l) {       // uniform (SGPR) trip count
      const int4 pa = sp[2 * l + 2];     // prefetch next quad (in-bounds: <64)
      const int4 pb = sp[2 * l + 3];
      const float v0 = uPT(qa.x, qa.y, AB, CD, sE);
      const float v1 = uPT(qa.z, qa.w, AB, CD, sE);
      const float v2 = uPT(qb.x, qb.y, AB, CD, sE);
      const float v3 = uPT(qb.z, qb.w, AB, CD, sE);
      um0 = fmaxf(fmaxf(um0, v0), v1);   // v_max3_f32
      um1 = fmaxf(fmaxf(um1, v2), v3);
      qa = pa; qb = pb;
    }
    // tail: 0..3 points, individually guarded, from prefetched qa/qb
    if (rem >= 1) um0 = fmaxf(um0, uPT(qa.x, qa.y, AB, CD, sE));
    if (rem >= 2) um0 = fmaxf(um0, uPT(qa.z, qa.w, AB, CD, sE));
    if (rem >= 3) um1 = fmaxf(um1, uPT(qb.x, qb.y, AB, CD, sE));
    umm[(size_t)p_ * 64 + d] = fmaxf(um0, um1);
  }

  // ---- wave + block reduce of the 54 accumulators ----
  #pragma unroll
  for (int i = 0; i < 9; ++i)  a1[i] = dpp_sum64(a1[i]);
  #pragma unroll
  for (int i = 0; i < 45; ++i) a2[i] = dpp_sum64(a2[i]);

  if (lane == 63) {
    #pragma unroll
    for (int i = 0; i < 9; ++i)  red[wid][i]     = a1[i];
    #pragma unroll
    for (int i = 0; i < 45; ++i) red[wid][9 + i] = a2[i];
  }
  __syncthreads();
  if (threadIdx.x < 54) {
    const int t = threadIdx.x;
    partials[blockIdx.x * 54 + t] = red[0][t] + red[1][t] + red[2][t] + red[3][t];
  }
}

// ---------------- Kernel 1b: reduce partials -> 54 moments ----------------

__global__ __launch_bounds__(256) void k_red(
    const float* __restrict__ partials, float* __restrict__ moments)
{
  const int c = blockIdx.x;
  float s = 0.f;
  for (int b = threadIdx.x; b < NBF; b += 256) s += partials[b * 54 + c];
  s = dpp_sum64(s);
  __shared__ float r4[4];
  const int lane = threadIdx.x & 63, wid = threadIdx.x >> 6;
  if (lane == 63) r4[wid] = s;
  __syncthreads();
  if (threadIdx.x == 0) moments[c] = r4[0] + r4[1] + r4[2] + r4[3];
}

// ---------------- Kernel 2: moments -> per-channel BN scale/shift ----------------

__global__ __launch_bounds__(64) void k_stats(
    const float* __restrict__ moments, const float* __restrict__ W,
    const float* __restrict__ gamma, const float* __restrict__ beta,
    float* __restrict__ scale, float* __restrict__ shift)
{
  const int d = threadIdx.x;
  float mom[54];
  #pragma unroll
  for (int i = 0; i < 54; ++i) mom[i] = moments[i];

  float w[9];
  #pragma unroll
  for (int c = 0; c < 9; ++c) w[c] = W[c * 64 + d];
  const float invN = 1.f / ((float)P_N * (float)M_N);
  float mu = 0.f;
  #pragma unroll
  for (int c = 0; c < 9; ++c) mu += mom[c] * w[c];
  mu *= invN;
  float e2 = 0.f;
  int k = 0;
  #pragma unroll
  for (int c = 0; c < 9; ++c) {
    #pragma unroll
    for (int c2 = c; c2 < 9; ++c2) {
      const float t = w[c] * w[c2] * mom[9 + k];
      e2 += (c == c2) ? t : 2.f * t;
      ++k;
    }
  }
  e2 *= invN;
  float var = e2 - mu * mu;
  var = var < 0.f ? 0.f : var;
  const float sc = gamma[d] * rsqrtf(var + 1e-5f);
  const float sh = fmaf(-mu, sc, beta[d]);
  scale[d] = sc;
  shift[d] = sh;
}

// ---------------- Kernel 3: finalize in place ----------------
// out holds f32 raw umax; out[p,d] = relu(max(sc*umax + sh, sh)).

__global__ __launch_bounds__(256) void k_apply(
    const int* __restrict__ npp, const float* __restrict__ scale,
    const float* __restrict__ shift, float* __restrict__ out)
{
  const int gid = blockIdx.x * 256 + threadIdx.x;   // 0 .. P_N*64/4 - 1
  const int p = gid >> 4;
  const int q = gid & 15;                            // float4 group of channels

  float4 u4 = ((const float4*)out)[gid];
  const float4 sc4 = ((const float4*)scale)[q];
  const float4 sh4 = ((const float4*)shift)[q];
  const int n = npp[p];
  const bool has_masked = n < M_N;

  float4 r;
  float t;
  t = fmaf(sc4.x, u4.x, sh4.x); if (has_masked) t = fmaxf(t, sh4.x); r.x = fmaxf(t, 0.f);
  t = fmaf(sc4.y, u4.y, sh4.y); if (has_masked) t = fmaxf(t, sh4.y); r.y = fmaxf(t, 0.f);
  t = fmaf(sc4.z, u4.z, sh4.z); if (has_masked) t = fmaxf(t, sh4.z); r.z = fmaxf(t, 0.f);
  t = fmaf(sc4.w, u4.w, sh4.w); if (has_masked) t = fmaxf(t, sh4.w); r.w = fmaxf(t, 0.f);
  ((float4*)out)[gid] = r;
}

// ---------------- launch ----------------

extern "C" void kernel_launch(void* const* d_in, const int* in_sizes, int n_in,
                              void* d_out, int out_size, void* d_ws, size_t ws_size,
                              hipStream_t stream) {
  const float* px    = (const float*)d_in[0];
  const float* py    = (const float*)d_in[1];
  const float* pz    = (const float*)d_in[2];
  const float* pi    = (const float*)d_in[3];
  const int*   npp   = (const int*)d_in[4];
  const int*   coors = (const int*)d_in[5];
  const float* W     = (const float*)d_in[6];
  const float* gamma = (const float*)d_in[7];
  const float* beta  = (const float*)d_in[8];
  float* out = (float*)d_out;

  float* wsf      = (float*)d_ws;
  float* partials = wsf;                    // NBF*54 = 135000 floats (block-major)
  float* moments  = wsf + 135000;           // 54
  float* scale    = wsf + 135072;           // 64
  float* shift    = wsf + 135136;           // 64

  k_fused<<<NBF, 256, 0, stream>>>(px, py, pz, pi, npp, coors, W, partials, out);
  k_red<<<54, 256, 0, stream>>>(partials, moments);
  k_stats<<<1, 64, 0, stream>>>(moments, W, gamma, beta, scale, shift);
  k_apply<<<P_N * 64 / 4 / 256, 256, 0, stream>>>(npp, scale, shift, out);
}

// Round 15
// 55.577 us; speedup vs baseline: 1.0373x; 1.0373x over previous
//
#include <hip/hip_runtime.h>

#define P_N 40000
#define M_N 100
#define NBF 2500    // k_fused blocks: 4 waves/block, 4 pillars/wave
#define NPART 80    // per-block partials: [0..44]=M2 corr, [45..53]=M1, [64..73]=R2 raw
#define NUSED 74

typedef _Float16 half2_t __attribute__((ext_vector_type(2)));

__device__ __forceinline__ float bcf(int x) { return __int_as_float(x); }
__device__ __forceinline__ int   bci(float x) { return __float_as_int(x); }
__device__ __forceinline__ float rlf(float v, int l) {
  return bcf(__builtin_amdgcn_readlane(bci(v), l));
}
__device__ __forceinline__ int pk16i(float a, float b) {
  return __builtin_bit_cast(int, __builtin_amdgcn_cvt_pkrtz(a, b));
}
__device__ __forceinline__ half2_t h2(int x) { return __builtin_bit_cast(half2_t, x); }
__device__ __forceinline__ float dot2(int a, int b, float acc) {
  return __builtin_amdgcn_fdot2(h2(a), h2(b), acc, false);
}

// DPP full-wave64 add-reduce on the VALU pipe. Lane 63 holds the sum.
__device__ __forceinline__ float dpp_sum64(float x) {
  x += bcf(__builtin_amdgcn_update_dpp(0, bci(x), 0x111, 0xf, 0xf, true)); // row_shr:1
  x += bcf(__builtin_amdgcn_update_dpp(0, bci(x), 0x112, 0xf, 0xf, true)); // row_shr:2
  x += bcf(__builtin_amdgcn_update_dpp(0, bci(x), 0x114, 0xf, 0xf, true)); // row_shr:4
  x += bcf(__builtin_amdgcn_update_dpp(0, bci(x), 0x118, 0xf, 0xf, true)); // row_shr:8
  x += bcf(__builtin_amdgcn_update_dpp(0, bci(x), 0x142, 0xf, 0xf, true)); // row_bcast:15
  x += bcf(__builtin_amdgcn_update_dpp(0, bci(x), 0x143, 0xf, 0xf, true)); // row_bcast:31
  return x;
}

// u for one point from point-major packs: (x,y)·AB + (z,i)·CD + sE
__device__ __forceinline__ float uPT(int xy, int zi, half2_t AB, half2_t CD, float sE) {
  return __builtin_amdgcn_fdot2(h2(xy), AB,
         __builtin_amdgcn_fdot2(h2(zi), CD, sE, false), false);
}

// ---------------- Kernel 1 (fused) ----------------
// Mean-expansion formulation: global accumulators are ONLY the 10 raw products
// among {x,y,z,i} (valid-masked) + a lane-indexed correction accumulator.
// Statistic s(lane): lanes 0..44 = M2 pair (c<=c2), 45..53 = M1 (c=lane-45).
// h-basis components: 0..3 = x,y,z,i; 4 = 1; 5 = xb; 6 = yb.
// term_p = base - m_c*S2 - m_c2*S1 + n*m_c*m_c2, where S_r = Σ_valid h_r,
// base = bothVec?0 : rc1>3 ? K(rc1)*S2 : K(rc2)*S1. R2 raw part added in k_stats.

__global__ __launch_bounds__(256) void k_fused(
    const float* __restrict__ px, const float* __restrict__ py,
    const float* __restrict__ pz, const float* __restrict__ pi,
    const int* __restrict__ npp, const int* __restrict__ coors,
    const float* __restrict__ W,
    float* __restrict__ partials, float* __restrict__ umm)
{
  const int lane = threadIdx.x & 63;
  const int wid  = threadIdx.x >> 6;    // 0..3
  const int d    = lane;

  __shared__ int4  stage[4][4][64];     // [wave][pillar][pair-slot]
  __shared__ float red[4][NPART];

  // ---- per-lane statistic assignment ----
  int c = 9, c2 = 9;                    // sentinel (lanes >= 54 idle)
  if (lane < 45) {
    int k = lane; c = 0;
    while (k >= 9 - c) { k -= 9 - c; ++c; }
    c2 = c + k;
  } else if (lane < 54) {
    c = lane - 45; c2 = 9;              // M1: pair with constant-1 feature
  }
  const int rc1 = (c  < 4) ? c  : (c  < 7) ? c  - 4 : (c  < 9) ? c  - 2 : 4;
  const int rc2 = (c2 < 4) ? c2 : (c2 < 7) ? c2 - 4 : (c2 < 9) ? c2 - 2 : 4;
  const bool bothVec = (rc1 < 4) && (rc2 < 4);
  const bool statln  = lane < 54;

  float w[9];
  #pragma unroll
  for (int q = 0; q < 9; ++q) w[q] = W[q * 64 + d];
  const float sA = w[0] + w[4], sB = w[1] + w[5], sC = w[2] + w[6], sD = w[3];
  const half2_t AB = h2(pk16i(sA, sB));
  const half2_t CD = h2(pk16i(sC, sD));
  const int H1 = 0x3C003C00;            // (1.0h, 1.0h)

  const bool act = lane < 50;
  const int wgid  = blockIdx.x * 4 + wid;
  const int pbase = __builtin_amdgcn_readfirstlane(wgid * 4);

  const int4 n4 = ((const int4*)npp)[wgid];
  int4 cc[4];
  #pragma unroll
  for (int it = 0; it < 4; ++it) cc[it] = ((const int4*)coors)[pbase + it];

  // ---- load rows, pack to f16, stage point-major to LDS ----
  int u0[4], u1[4], u2[4], u3[4];
  #pragma unroll
  for (int it = 0; it < 4; ++it) {
    const int p_ = pbase + it;
    float2 X = make_float2(0.f, 0.f), Y = X, Z = X, I = X;
    if (act) {
      X = ((const float2*)(px + (size_t)p_ * M_N))[lane];
      Y = ((const float2*)(py + (size_t)p_ * M_N))[lane];
      Z = ((const float2*)(pz + (size_t)p_ * M_N))[lane];
      I = ((const float2*)(pi + (size_t)p_ * M_N))[lane];
    }
    u0[it] = pk16i(X.x, X.y);
    u1[it] = pk16i(Y.x, Y.y);
    u2[it] = pk16i(Z.x, Z.y);
    u3[it] = pk16i(I.x, I.y);
    int4 pm;
    pm.x = pk16i(X.x, Y.x);
    pm.y = pk16i(Z.x, I.x);
    pm.z = pk16i(X.y, Y.y);
    pm.w = pk16i(Z.y, I.y);
    stage[wid][it][lane] = pm;
  }

  float R2a[10] = {};
  float corrAcc = 0.f;

  #pragma unroll
  for (int it = 0; it < 4; ++it) {
    const int p_ = pbase + it;
    const int n  = ((const int*)&n4)[it];
    const float nf = (float)n;

    // validity mask for this lane's two point slots
    const unsigned msk = ((2 * lane     < n) ? 0x0000FFFFu : 0u)
                       | ((2 * lane + 1 < n) ? 0xFFFF0000u : 0u);
    const int g0 = u0[it] & msk;
    const int g1 = u1[it] & msk;
    const int g2 = u2[it] & msk;
    const int g3 = u3[it] & msk;

    // full sums (means) + valid sums: 7 DPP chains
    float fx = dot2(u0[it], H1, 0.f);
    float fy = dot2(u1[it], H1, 0.f);
    float fz = dot2(u2[it], H1, 0.f);
    float vx = dot2(g0, H1, 0.f);
    float vy = dot2(g1, H1, 0.f);
    float vz = dot2(g2, H1, 0.f);
    float vi = dot2(g3, H1, 0.f);
    fx = dpp_sum64(fx); fy = dpp_sum64(fy); fz = dpp_sum64(fz);
    vx = dpp_sum64(vx); vy = dpp_sum64(vy); vz = dpp_sum64(vz); vi = dpp_sum64(vi);

    const int nc = n < 1 ? 1 : n;
    const float inv = __builtin_amdgcn_rcpf((float)nc);
    const float mx = rlf(fx, 63) * inv;
    const float my = rlf(fy, 63) * inv;
    const float mz = rlf(fz, 63) * inv;
    const float svx = rlf(vx, 63);
    const float svy = rlf(vy, 63);
    const float svz = rlf(vz, 63);
    const float svi = rlf(vi, 63);

    const float xb = fmaf((float)cc[it].w, 0.16f, 0.08f);            // X0 = 0
    const float yb = fmaf((float)cc[it].z, 0.16f, 0.08f - 39.68f);   // Y0 = -39.68

    // 10 global raw products among x,y,z,i (valid-masked)
    R2a[0] = dot2(g0, g0, R2a[0]);
    R2a[1] = dot2(g0, g1, R2a[1]);
    R2a[2] = dot2(g0, g2, R2a[2]);
    R2a[3] = dot2(g0, g3, R2a[3]);
    R2a[4] = dot2(g1, g1, R2a[4]);
    R2a[5] = dot2(g1, g2, R2a[5]);
    R2a[6] = dot2(g1, g3, R2a[6]);
    R2a[7] = dot2(g2, g2, R2a[7]);
    R2a[8] = dot2(g2, g3, R2a[8]);
    R2a[9] = dot2(g3, g3, R2a[9]);

    // per-lane correction term
    {
      const float nxb = nf * xb, nyb = nf * yb;
      const float S1 = (rc1 == 0) ? svx : (rc1 == 1) ? svy : (rc1 == 2) ? svz
                     : (rc1 == 3) ? svi : (rc1 == 4) ? nf  : (rc1 == 5) ? nxb : nyb;
      const float S2 = (rc2 == 0) ? svx : (rc2 == 1) ? svy : (rc2 == 2) ? svz
                     : (rc2 == 3) ? svi : (rc2 == 4) ? nf  : (rc2 == 5) ? nxb : nyb;
      float base = 0.f;
      if (!bothVec)
        base = (rc1 > 3) ? ((rc1 == 4) ? S2 : (rc1 == 5) ? xb * S2 : yb * S2)
                         : ((rc2 == 4) ? S1 : (rc2 == 5) ? xb * S1 : yb * S1);
      const float mv1 = (c  == 4) ? mx : (c  == 5) ? my : (c  == 6) ? mz : 0.f;
      const float mv2 = (c2 == 4) ? mx : (c2 == 5) ? my : (c2 == 6) ? mz : 0.f;
      const float term = base - mv1 * S2 - mv2 * S1 + nf * mv1 * mv2;
      if (statln) corrAcc += term;
    }

    // per-pillar constant term of the linear output
    const float sE = fmaf(-mx, w[4], fmaf(-my, w[5], fmaf(-mz, w[6],
                     fmaf(xb, w[7], yb * w[8]))));

    // umax: uniform LDS broadcast, 4 pts / iter, 2 independent accs
    const int4* sp = &stage[wid][it][0];
    float um0 = -3.0e38f, um1 = -3.0e38f;
    const int nq = n >> 2;
    for (int l = 0; l < nq; ++l) {       // uniform (SGPR) trip count
      const int4 qa = sp[2 * l];
      const int4 qb = sp[2 * l + 1];
      const float v0 = uPT(qa.x, qa.y, AB, CD, sE);
      const float v1 = uPT(qa.z, qa.w, AB, CD, sE);
      const float v2 = uPT(qb.x, qb.y, AB, CD, sE);
      const float v3 = uPT(qb.z, qb.w, AB, CD, sE);
      um0 = fmaxf(fmaxf(um0, v0), v1);   // v_max3_f32
      um1 = fmaxf(fmaxf(um1, v2), v3);
    }
    const int m_ = nq * 4;
    if (n - m_ >= 2) {
      const int4 qa = sp[m_ >> 1];
      const float v0 = uPT(qa.x, qa.y, AB, CD, sE);
      const float v1 = uPT(qa.z, qa.w, AB, CD, sE);
      um0 = fmaxf(fmaxf(um0, v0), v1);
    }
    if (n & 1) {                          // last point (int2 index n-1)
      const int2 qq = ((const int2*)sp)[n - 1];
      um1 = fmaxf(um1, uPT(qq.x, qq.y, AB, CD, sE));
    }
    umm[(size_t)p_ * 64 + d] = fmaxf(um0, um1);
  }

  // ---- epilogue: 10 chains for R2, lane-indexed corr, block reduce ----
  #pragma unroll
  for (int i = 0; i < 10; ++i) R2a[i] = dpp_sum64(R2a[i]);

  red[wid][lane] = corrAcc;              // lanes >=54 wrote 0
  if (lane == 63) {
    #pragma unroll
    for (int i = 0; i < 10; ++i) red[wid][64 + i] = R2a[i];
  }
  __syncthreads();
  if (threadIdx.x < NUSED) {
    const int t = threadIdx.x;
    partials[blockIdx.x * NPART + t] = red[0][t] + red[1][t] + red[2][t] + red[3][t];
  }
}

// ---------------- Kernel 1b: reduce partials -> 74 stats ----------------

__global__ __launch_bounds__(256) void k_red(
    const float* __restrict__ partials, float* __restrict__ stats)
{
  const int c = blockIdx.x;              // 0..73
  float s = 0.f;
  for (int b = threadIdx.x; b < NBF; b += 256) s += partials[b * NPART + c];
  s = dpp_sum64(s);
  __shared__ float r4[4];
  const int lane = threadIdx.x & 63, wid = threadIdx.x >> 6;
  if (lane == 63) r4[wid] = s;
  __syncthreads();
  if (threadIdx.x == 0) stats[c] = r4[0] + r4[1] + r4[2] + r4[3];
}

// ---------------- Kernel 2: stats -> per-channel BN scale/shift ----------------

__global__ __launch_bounds__(64) void k_stats(
    const float* __restrict__ stats, const float* __restrict__ W,
    const float* __restrict__ gamma, const float* __restrict__ beta,
    float* __restrict__ scale, float* __restrict__ shift)
{
  const int d = threadIdx.x;
  __shared__ float Cs[NUSED];
  // FIX (round-14 bug): 64 threads must cover all 74 entries — the second
  // guarded load brings in the 10 raw second moments at Cs[64..73].
  Cs[d] = stats[d];
  if (d < NUSED - 64) Cs[64 + d] = stats[64 + d];
  __syncthreads();

  // assemble mom1[9], mom2[45]
  float mom1[9];
  #pragma unroll
  for (int q = 0; q < 9; ++q) mom1[q] = Cs[45 + q];
  float mom2[45];
  {
    int k = 0;
    #pragma unroll
    for (int cA = 0; cA < 9; ++cA) {
      #pragma unroll
      for (int cB = cA; cB < 9; ++cB) {
        float v = Cs[k];
        if (cA <= 6 && cB <= 6) {
          const int a = (cA < 4) ? cA : cA - 4;
          const int b = (cB < 4) ? cB : cB - 4;
          const int lo = a < b ? a : b;
          const int hi = a < b ? b : a;
          const int idx = lo * 4 - lo * (lo - 1) / 2 + (hi - lo);
          v += Cs[64 + idx];
        }
        mom2[k] = v;
        ++k;
      }
    }
  }

  float w[9];
  #pragma unroll
  for (int q = 0; q < 9; ++q) w[q] = W[q * 64 + d];
  const float invN = 1.f / ((float)P_N * (float)M_N);
  float mu = 0.f;
  #pragma unroll
  for (int q = 0; q < 9; ++q) mu += mom1[q] * w[q];
  mu *= invN;
  float e2 = 0.f;
  int k = 0;
  #pragma unroll
  for (int cA = 0; cA < 9; ++cA) {
    #pragma unroll
    for (int cB = cA; cB < 9; ++cB) {
      const float t = w[cA] * w[cB] * mom2[k];
      e2 += (cA == cB) ? t : 2.f * t;
      ++k;
    }
  }
  e2 *= invN;
  float var = e2 - mu * mu;
  var = var < 0.f ? 0.f : var;
  const float sc = gamma[d] * rsqrtf(var + 1e-5f);
  const float sh = fmaf(-mu, sc, beta[d]);
  scale[d] = sc;
  shift[d] = sh;
}

// ---------------- Kernel 3: finalize in place ----------------

__global__ __launch_bounds__(256) void k_apply(
    const int* __restrict__ npp, const float* __restrict__ scale,
    const float* __restrict__ shift, float* __restrict__ out)
{
  const int gid = blockIdx.x * 256 + threadIdx.x;   // 0 .. P_N*64/4 - 1
  const int p = gid >> 4;
  const int q = gid & 15;

  float4 u4 = ((const float4*)out)[gid];
  const float4 sc4 = ((const float4*)scale)[q];
  const float4 sh4 = ((const float4*)shift)[q];
  const int n = npp[p];
  const bool has_masked = n < M_N;

  float4 r;
  float t;
  t = fmaf(sc4.x, u4.x, sh4.x); if (has_masked) t = fmaxf(t, sh4.x); r.x = fmaxf(t, 0.f);
  t = fmaf(sc4.y, u4.y, sh4.y); if (has_masked) t = fmaxf(t, sh4.y); r.y = fmaxf(t, 0.f);
  t = fmaf(sc4.z, u4.z, sh4.z); if (has_masked) t = fmaxf(t, sh4.z); r.z = fmaxf(t, 0.f);
  t = fmaf(sc4.w, u4.w, sh4.w); if (has_masked) t = fmaxf(t, sh4.w); r.w = fmaxf(t, 0.f);
  ((float4*)out)[gid] = r;
}

// ---------------- launch ----------------

extern "C" void kernel_launch(void* const* d_in, const int* in_sizes, int n_in,
                              void* d_out, int out_size, void* d_ws, size_t ws_size,
                              hipStream_t stream) {
  const float* px    = (const float*)d_in[0];
  const float* py    = (const float*)d_in[1];
  const float* pz    = (const float*)d_in[2];
  const float* pi    = (const float*)d_in[3];
  const int*   npp   = (const int*)d_in[4];
  const int*   coors = (const int*)d_in[5];
  const float* W     = (const float*)d_in[6];
  const float* gamma = (const float*)d_in[7];
  const float* beta  = (const float*)d_in[8];
  float* out = (float*)d_out;

  float* wsf      = (float*)d_ws;
  float* partials = wsf;                    // NBF*NPART = 200000 floats
  float* stats    = wsf + 200000;           // 74
  float* scale    = wsf + 200128;           // 64
  float* shift    = wsf + 200192;           // 64

  k_fused<<<NBF, 256, 0, stream>>>(px, py, pz, pi, npp, coors, W, partials, out);
  k_red<<<NUSED, 256, 0, stream>>>(partials, stats);
  k_stats<<<1, 64, 0, stream>>>(stats, W, gamma, beta, scale, shift);
  k_apply<<<P_N * 64 / 4 / 256, 256, 0, stream>>>(npp, scale, shift, out);
}